// Round 1
// baseline (476.281 us; speedup 1.0000x reference)
//
#include <hip/hip_runtime.h>
#include <cstdint>
#include <cstddef>

typedef unsigned short u16;
typedef unsigned long long u64;
using short8 = __attribute__((ext_vector_type(8))) short;
using f32x4  = __attribute__((ext_vector_type(4))) float;

// (1/0.07) * log2(e)
#define KEXP 20.609929155556620f

__device__ __forceinline__ u16 f2bf(float f) {
  unsigned u = __float_as_uint(f);
  u += 0x7fffu + ((u >> 16) & 1u);
  return (u16)(u >> 16);
}
__device__ __forceinline__ float bf2f(u16 h) { return __uint_as_float(((unsigned)h) << 16); }

typedef const unsigned int GASu32 __attribute__((address_space(1)));
typedef unsigned int LASu32 __attribute__((address_space(3)));

__device__ __forceinline__ void gload16(const u16* src, u16* dstLds) {
  __builtin_amdgcn_global_load_lds((GASu32*)src, (LASu32*)dstLds, 16, 0, 0);
}

// ---------------- transpose x: [B][C][S] f32 -> xT [B][S][C] bf16 ----------------
__global__ __launch_bounds__(256) void transpose_x(const float* __restrict__ x, u16* __restrict__ xT) {
  __shared__ float t[32][33];
  int b = blockIdx.z, c0 = blockIdx.y * 32, s0 = blockIdx.x * 32;
  int tid = threadIdx.x;
  int ci = tid >> 3, s4 = (tid & 7) * 4;
  float4 v = *(const float4*)(x + ((size_t)b * 512 + c0 + ci) * 8192 + s0 + s4);
  t[ci][s4 + 0] = v.x; t[ci][s4 + 1] = v.y; t[ci][s4 + 2] = v.z; t[ci][s4 + 3] = v.w;
  __syncthreads();
  int si = tid >> 3, c4 = (tid & 7) * 4;
  ushort4 o;
  o.x = f2bf(t[c4 + 0][si]); o.y = f2bf(t[c4 + 1][si]);
  o.z = f2bf(t[c4 + 2][si]); o.w = f2bf(t[c4 + 3][si]);
  *(ushort4*)(xT + ((size_t)b * 8192 + s0 + si) * 512 + c0 + c4) = o;
}

// ---------------- transpose W: [512][128] f32 -> Wt [128][512] bf16 ----------------
__global__ __launch_bounds__(256) void transpose_w(const float* __restrict__ W, u16* __restrict__ Wt) {
  int idx = blockIdx.x * 256 + threadIdx.x;  // 65536
  int d = idx >> 9, c = idx & 511;
  Wt[idx] = f2bf(W[c * 128 + d]);
}

// ---------------- normalize keys rows (in place, bf16 [32768][128]) ----------------
__global__ __launch_bounds__(256) void normalize_keys(u16* __restrict__ keys) {
  int wv = threadIdx.x >> 6, lane = threadIdx.x & 63;
  int row = blockIdx.x * 4 + wv;
  unsigned* p = (unsigned*)(keys + (size_t)row * 128) + lane;
  unsigned v = *p;
  float a = bf2f((u16)(v & 0xffffu)), b = bf2f((u16)(v >> 16));
  float s = a * a + b * b;
  #pragma unroll
  for (int m = 1; m < 64; m <<= 1) s += __shfl_xor(s, m, 64);
  float sc = 1.f / fmaxf(sqrtf(s), 1e-12f);
  *p = (unsigned)f2bf(a * sc) | ((unsigned)f2bf(b * sc) << 16);
}

// ---------------- row sums of E (bf16 [28*1024][1024]) ----------------
__global__ __launch_bounds__(256) void rowsum_e(const u16* __restrict__ E, float* __restrict__ rs) {
  int wv = threadIdx.x >> 6, lane = threadIdx.x & 63;
  int row = blockIdx.x * 4 + wv;
  const u16* p = E + (size_t)row * 1024;
  float s = 0.f;
  #pragma unroll
  for (int it = 0; it < 4; ++it) {
    ushort4 v = *(const ushort4*)(p + it * 256 + lane * 4);
    s += bf2f(v.x) + bf2f(v.y) + bf2f(v.z) + bf2f(v.w);
  }
  #pragma unroll
  for (int m = 1; m < 64; m <<= 1) s += __shfl_xor(s, m, 64);
  if (lane == 0) rs[row] = s;
}

// ---------------- col sums of E ----------------
__global__ __launch_bounds__(256) void colsum_e(const u16* __restrict__ E, float* __restrict__ cs) {
  int bid = blockIdx.x;            // 28*32
  int z = bid >> 5, rem = bid & 31;
  int cch = rem & 3, rch = rem >> 2;
  int c = cch * 256 + threadIdx.x;
  const u16* p = E + ((size_t)z << 20) + (size_t)rch * 131072 + c;
  float s = 0.f;
  #pragma unroll 8
  for (int r = 0; r < 128; ++r) s += bf2f(p[(size_t)r * 1024]);
  atomicAdd(&cs[z * 1024 + c], s);
}

// ---------------- t=0: P0 = row-normalized E0, S0 = col-normalized E0 ----------------
__global__ __launch_bounds__(256) void k3_t0(const u16* __restrict__ E, const float* __restrict__ rsum,
                                             const float* __restrict__ csum,
                                             u16* __restrict__ P0, u16* __restrict__ S0) {
  int b = blockIdx.z, r = blockIdx.x;
  int zE = b * 7;
  const u16* e = E + ((size_t)zE << 20) + (size_t)r * 1024;
  float rr = 1.f / rsum[zE * 1024 + r];
  int c = threadIdx.x * 4;
  ushort4 v = *(const ushort4*)(e + c);
  float4 cv = *(const float4*)(csum + zE * 1024 + c);
  ushort4 o1, o2;
  float v0 = bf2f(v.x), v1 = bf2f(v.y), v2 = bf2f(v.z), v3 = bf2f(v.w);
  o1.x = f2bf(v0 * rr); o1.y = f2bf(v1 * rr); o1.z = f2bf(v2 * rr); o1.w = f2bf(v3 * rr);
  o2.x = f2bf(v0 / cv.x); o2.y = f2bf(v1 / cv.y); o2.z = f2bf(v2 / cv.z); o2.w = f2bf(v3 / cv.w);
  size_t base = ((size_t)b << 20) + (size_t)r * 1024 + c;
  *(ushort4*)(P0 + base) = o1;
  *(ushort4*)(S0 + base) = o2;
}

// ---------------- t>=1: Bp[t][n][k] = E[k][n]/rowsum[k], Bs[t][n][k] = E[k][n]/colsum[n] ----------------
__global__ __launch_bounds__(256) void k3_tr(const u16* __restrict__ E, const float* __restrict__ rsum,
                                             const float* __restrict__ csum,
                                             u16* __restrict__ Bp, u16* __restrict__ Bs) {
  __shared__ u16 t[64][66];
  int z = blockIdx.z; int b = z / 6, tt = z % 6 + 1;
  int zE = b * 7 + tt;
  int er0 = blockIdx.x * 64, ec0 = blockIdx.y * 64;
  const u16* e = E + ((size_t)zE << 20);
  int tid = threadIdx.x;
  int ri = tid >> 4, c4 = (tid & 15) * 4;
  #pragma unroll
  for (int p = 0; p < 4; ++p) {
    ushort4 v = *(const ushort4*)(e + (size_t)(er0 + ri + p * 16) * 1024 + ec0 + c4);
    t[ri + p * 16][c4 + 0] = v.x; t[ri + p * 16][c4 + 1] = v.y;
    t[ri + p * 16][c4 + 2] = v.z; t[ri + p * 16][c4 + 3] = v.w;
  }
  __syncthreads();
  size_t outBase = (size_t)(b * 6 + tt - 1) << 20;
  float ir0 = 1.f / rsum[zE * 1024 + er0 + c4 + 0];
  float ir1 = 1.f / rsum[zE * 1024 + er0 + c4 + 1];
  float ir2 = 1.f / rsum[zE * 1024 + er0 + c4 + 2];
  float ir3 = 1.f / rsum[zE * 1024 + er0 + c4 + 3];
  #pragma unroll
  for (int p = 0; p < 4; ++p) {
    int roL = ri + p * 16;
    int ro = ec0 + roL;
    float ic = 1.f / csum[zE * 1024 + ro];
    float v0 = bf2f(t[c4 + 0][roL]), v1 = bf2f(t[c4 + 1][roL]);
    float v2 = bf2f(t[c4 + 2][roL]), v3 = bf2f(t[c4 + 3][roL]);
    ushort4 op, os;
    op.x = f2bf(v0 * ir0); op.y = f2bf(v1 * ir1); op.z = f2bf(v2 * ir2); op.w = f2bf(v3 * ir3);
    os.x = f2bf(v0 * ic);  os.y = f2bf(v1 * ic);  os.z = f2bf(v2 * ic);  os.w = f2bf(v3 * ic);
    size_t off = outBase + (size_t)ro * 1024 + er0 + c4;
    *(ushort4*)(Bp + off) = op;
    *(ushort4*)(Bs + off) = os;
  }
}

// ---------------- generic NT GEMM, bf16 in, 128x128 tile, BK=64 ----------------
struct GemmBatch { const u16* A[8]; const u16* B[8]; u16* C[8]; };
enum { M_HEAD = 0, M_EXP = 1, M_PLAIN = 2, M_AAR = 3 };

__device__ __forceinline__ void stage_tile(const u16* __restrict__ g, int ld, int r0, int k0, u16* lds) {
  int tid = threadIdx.x;
  int lane = tid & 63, wv = tid >> 6;
  #pragma unroll
  for (int j = 0; j < 4; ++j) {
    int gi = ((wv << 2) + j) * 64 + lane;   // 16B granule index
    int row = gi >> 3;
    int wp = (gi & 7) << 4;                 // physical byte in 128B row
    int lc = wp ^ ((row & 7) << 4);         // logical byte (inverse swizzle on source)
    const u16* src = g + (size_t)(r0 + row) * ld + k0 + (lc >> 1);
    gload16(src, lds + ((wv << 2) + j) * 512);
  }
}

__device__ __forceinline__ short8 frag_ld(const u16* s, int row, int kb) {
  int off = row * 128 + (kb ^ ((row & 7) << 4));
  return *(const short8*)((const char*)s + off);
}

template <int MODE>
__global__ __launch_bounds__(256) void gemm_nt(const u16* __restrict__ gA, const u16* __restrict__ gB,
                                               u16* __restrict__ gC, GemmBatch batch,
                                               const float* __restrict__ bias,
                                               float* __restrict__ rowsumR, u64* __restrict__ amax,
                                               float* __restrict__ diagv) {
  __shared__ u16 As[128 * 64];
  __shared__ u16 Bs[128 * 64];
  int tid = threadIdx.x, lane = tid & 63, wv = tid >> 6;
  int wr = wv >> 1, wc = wv & 1;
  int z = blockIdx.z;
  const u16 *A, *B; u16* C;
  int K, lda, ldb, ldc;
  if constexpr (MODE == M_HEAD) {
    A = gA; B = gB; C = gC; K = 512; lda = 512; ldb = 512; ldc = 128;
  } else if constexpr (MODE == M_EXP) {
    int b = z / 7, t = z % 7;
    size_t offA = (size_t)(b * 8 + t) * 131072;
    A = gA + offA; B = gA + offA + 131072; C = gC + ((size_t)z << 20);
    K = 128; lda = 128; ldb = 128; ldc = 1024;
  } else if constexpr (MODE == M_PLAIN) {
    A = batch.A[z]; B = batch.B[z]; C = batch.C[z];
    K = 1024; lda = 1024; ldb = 1024; ldc = 1024;
  } else {
    A = gA + ((size_t)z << 20); B = gB + ((size_t)z << 20); C = nullptr;
    K = 1024; lda = 1024; ldb = 1024; ldc = 1024;
  }
  int m0 = blockIdx.x * 128, n0 = blockIdx.y * 128;

  f32x4 acc[4][4] = {};

  for (int kt = 0; kt < K; kt += 64) {
    stage_tile(A, lda, m0, kt, As);
    stage_tile(B, ldb, n0, kt, Bs);
    __syncthreads();
    #pragma unroll
    for (int ks = 0; ks < 2; ++ks) {
      short8 af[4], bfv[4];
      #pragma unroll
      for (int f = 0; f < 4; ++f) {
        af[f]  = frag_ld(As, (wr << 6) + (f << 4) + (lane & 15), (ks << 6) + ((lane >> 4) << 4));
        bfv[f] = frag_ld(Bs, (wc << 6) + (f << 4) + (lane & 15), (ks << 6) + ((lane >> 4) << 4));
      }
      #pragma unroll
      for (int fr = 0; fr < 4; ++fr)
        #pragma unroll
        for (int fc = 0; fc < 4; ++fc)
          acc[fr][fc] = __builtin_amdgcn_mfma_f32_16x16x32_bf16(af[fr], bfv[fc], acc[fr][fc], 0, 0, 0);
    }
    __syncthreads();
  }

  if constexpr (MODE == M_AAR) {
    #pragma unroll
    for (int fr = 0; fr < 4; ++fr) {
      #pragma unroll
      for (int j = 0; j < 4; ++j) {
        float rs = 0.f, mv = -1.f; int mc = 0;
        #pragma unroll
        for (int fc = 0; fc < 4; ++fc) {
          float v = acc[fr][fc][j];
          rs += v;
          int c = n0 + (wc << 6) + (fc << 4) + (lane & 15);
          if (v > mv) { mv = v; mc = c; }
        }
        u64 pk = ((u64)__float_as_uint(mv) << 32) | (u64)(unsigned)(1023 - mc);
        #pragma unroll
        for (int m = 1; m < 16; m <<= 1) {
          rs += __shfl_xor(rs, m, 64);
          u64 o = __shfl_xor(pk, m, 64);
          pk = (o > pk) ? o : pk;
        }
        if ((lane & 15) == 0) {
          int row = m0 + (wr << 6) + (fr << 4) + ((lane >> 4) << 2) + j;
          atomicAdd(&rowsumR[(z << 10) + row], rs);
          atomicMax(&amax[(z << 10) + row], pk);
        }
      }
      if (m0 == n0 && wr == wc) {
        int jj = (lane & 15) - ((lane >> 4) << 2);
        if (jj >= 0 && jj < 4) {
          int row = m0 + (wr << 6) + (fr << 4) + (lane & 15);
          float dv = (jj == 0) ? acc[fr][fr][0] : (jj == 1) ? acc[fr][fr][1]
                    : (jj == 2) ? acc[fr][fr][2] : acc[fr][fr][3];
          diagv[(z << 10) + row] = dv;
        }
      }
    }
  } else {
    #pragma unroll
    for (int fr = 0; fr < 4; ++fr)
      #pragma unroll
      for (int fc = 0; fc < 4; ++fc)
        #pragma unroll
        for (int j = 0; j < 4; ++j) {
          int row = m0 + (wr << 6) + (fr << 4) + ((lane >> 4) << 2) + j;
          int col = n0 + (wc << 6) + (fc << 4) + (lane & 15);
          float v = acc[fr][fc][j];
          if constexpr (MODE == M_HEAD) v += bias[col];
          if constexpr (MODE == M_EXP) v = exp2f(v * KEXP);
          C[(size_t)row * ldc + col] = f2bf(v);
        }
  }
}

// ---------------- per-walk finalize: loss + acc ----------------
__global__ __launch_bounds__(256) void finalize_k(const float* __restrict__ rowsumR, const u64* __restrict__ amax,
                                                  const float* __restrict__ diagv, float* __restrict__ out, int w) {
  __shared__ float sl[256], sa[256];
  int tid = threadIdx.x;
  float ls = 0.f, ac = 0.f;
  for (int idx = tid; idx < 4096; idx += 256) {
    int n = idx & 1023;
    float rs = rowsumR[idx];
    float dv = diagv[idx];
    ls += logf(rs + 1024.f * 1e-20f) - logf(dv + 1e-20f);
    unsigned pred = 1023u - (unsigned)(amax[idx] & 0xffffffffULL);
    ac += (pred == (unsigned)n) ? 1.f : 0.f;
  }
  sl[tid] = ls; sa[tid] = ac;
  __syncthreads();
  for (int s2 = 128; s2 > 0; s2 >>= 1) {
    if (tid < s2) { sl[tid] += sl[tid + s2]; sa[tid] += sa[tid + s2]; }
    __syncthreads();
  }
  if (tid == 0) {
    float loss = sl[0] / 4096.f, acv = sa[0] / 4096.f;
    out[1 + w] = loss;
    out[7 + w] = acv;
    if (w == 5) out[0] = loss;
  }
}

extern "C" void kernel_launch(void* const* d_in, const int* in_sizes, int n_in,
                              void* d_out, int out_size, void* d_ws, size_t ws_size,
                              hipStream_t stream) {
  (void)in_sizes; (void)n_in; (void)out_size; (void)ws_size;
  const float* x  = (const float*)d_in[0];
  const float* Wh = (const float*)d_in[1];
  const float* bh = (const float*)d_in[2];
  float* out = (float*)d_out;
  char* ws = (char*)d_ws;
  const size_t MB = 1ull << 20;

  u16* xT   = (u16*)(ws);                 // 32MB, dead after head gemm
  u16* PA   = (u16*)(ws);                 // chain ping-pong overlays xT
  u16* PB   = (u16*)(ws + 8 * MB);
  u16* SA   = (u16*)(ws + 16 * MB);
  u16* SB   = (u16*)(ws + 24 * MB);
  u16* keys = (u16*)(ws + 32 * MB);       // 8MB
  u16* Wt   = (u16*)(ws + 40 * MB);       // 128KB
  float* rsumE = (float*)(ws + 41 * MB);  // 112KB
  float* csumE = (float*)(ws + 41 * MB + 131072);
  u16* E    = (u16*)(ws + 42 * MB);       // 56MB
  u16* P0   = (u16*)(ws + 98 * MB);       // 8MB
  u16* S0   = (u16*)(ws + 106 * MB);      // 8MB
  u16* Bp   = (u16*)(ws + 114 * MB);      // 48MB
  u16* Bs   = (u16*)(ws + 162 * MB);      // 48MB
  float* rowsumR = (float*)(ws + 210 * MB);          // 16KB
  u64*   amax    = (u64*)(ws + 210 * MB + 16384);    // 32KB
  float* diagv   = (float*)(ws + 210 * MB + 49152);  // 16KB

  transpose_x<<<dim3(256, 16, 4), 256, 0, stream>>>(x, xT);
  transpose_w<<<dim3(256), 256, 0, stream>>>(Wh, Wt);
  gemm_nt<M_HEAD><<<dim3(256, 1, 1), 256, 0, stream>>>(xT, Wt, keys, GemmBatch{}, bh, nullptr, nullptr, nullptr);
  normalize_keys<<<dim3(8192), 256, 0, stream>>>(keys);
  gemm_nt<M_EXP><<<dim3(8, 8, 28), 256, 0, stream>>>(keys, nullptr, E, GemmBatch{}, nullptr, nullptr, nullptr, nullptr);
  rowsum_e<<<dim3(7168), 256, 0, stream>>>(E, rsumE);
  hipMemsetAsync(csumE, 0, 114688, stream);
  colsum_e<<<dim3(28 * 32), 256, 0, stream>>>(E, csumE);
  k3_t0<<<dim3(1024, 1, 4), 256, 0, stream>>>(E, rsumE, csumE, P0, S0);
  k3_tr<<<dim3(16, 16, 24), 256, 0, stream>>>(E, rsumE, csumE, Bp, Bs);

  u16* Pp = P0; u16* Sp = S0;
  u16* pbuf[2] = {PA, PB};
  u16* sbuf[2] = {SA, SB};
  for (int i = 1; i <= 6; ++i) {
    u16* Pc = pbuf[(i - 1) & 1];
    u16* Sc = sbuf[(i - 1) & 1];
    GemmBatch gb{};
    for (int b = 0; b < 4; ++b) {
      gb.A[b]     = Pp + (size_t)b * 1048576;
      gb.B[b]     = Bp + (size_t)(b * 6 + i - 1) * 1048576;
      gb.C[b]     = Pc + (size_t)b * 1048576;
      gb.A[4 + b] = Sp + (size_t)b * 1048576;
      gb.B[4 + b] = Bs + (size_t)(b * 6 + i - 1) * 1048576;
      gb.C[4 + b] = Sc + (size_t)b * 1048576;
    }
    gemm_nt<M_PLAIN><<<dim3(8, 8, 8), 256, 0, stream>>>(nullptr, nullptr, nullptr, gb, nullptr, nullptr, nullptr, nullptr);
    hipMemsetAsync(rowsumR, 0, 49152, stream);
    gemm_nt<M_AAR><<<dim3(8, 8, 4), 256, 0, stream>>>(Pc, Sc, nullptr, GemmBatch{}, nullptr, rowsumR, amax, diagv);
    finalize_k<<<dim3(1), 256, 0, stream>>>(rowsumR, amax, diagv, out, i - 1);
    Pp = Pc; Sp = Sc;
  }
}

// Round 3
// 382.367 us; speedup vs baseline: 1.2456x; 1.2456x over previous
//
#include <hip/hip_runtime.h>
#include <cstdint>
#include <cstddef>

typedef unsigned short u16;
typedef unsigned long long u64;
using short8 = __attribute__((ext_vector_type(8))) short;
using f32x4  = __attribute__((ext_vector_type(4))) float;

// (1/0.07) * log2(e)
#define KEXP 20.609929155556620f

__device__ __forceinline__ u16 f2bf(float f) {
  unsigned u = __float_as_uint(f);
  u += 0x7fffu + ((u >> 16) & 1u);
  return (u16)(u >> 16);
}
__device__ __forceinline__ float bf2f(u16 h) { return __uint_as_float(((unsigned)h) << 16); }

typedef const unsigned int GASu32 __attribute__((address_space(1)));
typedef unsigned int LASu32 __attribute__((address_space(3)));

__device__ __forceinline__ void gload16(const u16* src, u16* dstLds) {
  __builtin_amdgcn_global_load_lds((GASu32*)src, (LASu32*)dstLds, 16, 0, 0);
}

// ---------------- transpose x: [B][C][S] f32 -> xT [B][S][C] bf16 ----------------
__global__ __launch_bounds__(256) void transpose_x(const float* __restrict__ x, u16* __restrict__ xT) {
  __shared__ float t[32][33];
  int b = blockIdx.z, c0 = blockIdx.y * 32, s0 = blockIdx.x * 32;
  int tid = threadIdx.x;
  int ci = tid >> 3, s4 = (tid & 7) * 4;
  float4 v = *(const float4*)(x + ((size_t)b * 512 + c0 + ci) * 8192 + s0 + s4);
  t[ci][s4 + 0] = v.x; t[ci][s4 + 1] = v.y; t[ci][s4 + 2] = v.z; t[ci][s4 + 3] = v.w;
  __syncthreads();
  int si = tid >> 3, c4 = (tid & 7) * 4;
  ushort4 o;
  o.x = f2bf(t[c4 + 0][si]); o.y = f2bf(t[c4 + 1][si]);
  o.z = f2bf(t[c4 + 2][si]); o.w = f2bf(t[c4 + 3][si]);
  *(ushort4*)(xT + ((size_t)b * 8192 + s0 + si) * 512 + c0 + c4) = o;
}

// ---------------- transpose W: [512][128] f32 -> Wt [128][512] bf16 ----------------
__global__ __launch_bounds__(256) void transpose_w(const float* __restrict__ W, u16* __restrict__ Wt) {
  int idx = blockIdx.x * 256 + threadIdx.x;  // 65536
  int d = idx >> 9, c = idx & 511;
  Wt[idx] = f2bf(W[c * 128 + d]);
}

// ---------------- normalize keys rows (in place, bf16 [32768][128]) ----------------
__global__ __launch_bounds__(256) void normalize_keys(u16* __restrict__ keys) {
  int wv = threadIdx.x >> 6, lane = threadIdx.x & 63;
  int row = blockIdx.x * 4 + wv;
  unsigned* p = (unsigned*)(keys + (size_t)row * 128) + lane;
  unsigned v = *p;
  float a = bf2f((u16)(v & 0xffffu)), b = bf2f((u16)(v >> 16));
  float s = a * a + b * b;
  #pragma unroll
  for (int m = 1; m < 64; m <<= 1) s += __shfl_xor(s, m, 64);
  float sc = 1.f / fmaxf(sqrtf(s), 1e-12f);
  *p = (unsigned)f2bf(a * sc) | ((unsigned)f2bf(b * sc) << 16);
}

// ---------------- t=0: P0 = row-normalized E0, S0 = col-normalized E0 ----------------
__global__ __launch_bounds__(256) void k3_t0(const u16* __restrict__ E, const float* __restrict__ rsum,
                                             const float* __restrict__ csum,
                                             u16* __restrict__ P0, u16* __restrict__ S0) {
  int b = blockIdx.z, r = blockIdx.x;
  int zE = b * 7;
  const u16* e = E + ((size_t)zE << 20) + (size_t)r * 1024;
  float rr = 1.f / rsum[zE * 1024 + r];
  int c = threadIdx.x * 4;
  ushort4 v = *(const ushort4*)(e + c);
  float4 cv = *(const float4*)(csum + zE * 1024 + c);
  ushort4 o1, o2;
  float v0 = bf2f(v.x), v1 = bf2f(v.y), v2 = bf2f(v.z), v3 = bf2f(v.w);
  o1.x = f2bf(v0 * rr); o1.y = f2bf(v1 * rr); o1.z = f2bf(v2 * rr); o1.w = f2bf(v3 * rr);
  o2.x = f2bf(v0 / cv.x); o2.y = f2bf(v1 / cv.y); o2.z = f2bf(v2 / cv.z); o2.w = f2bf(v3 / cv.w);
  size_t base = ((size_t)b << 20) + (size_t)r * 1024 + c;
  *(ushort4*)(P0 + base) = o1;
  *(ushort4*)(S0 + base) = o2;
}

// ---------------- t>=1: Bp[t][n][k] = E[k][n]/rowsum[k], Bs[t][n][k] = E[k][n]/colsum[n] ----------------
__global__ __launch_bounds__(256) void k3_tr(const u16* __restrict__ E, const float* __restrict__ rsum,
                                             const float* __restrict__ csum,
                                             u16* __restrict__ Bp, u16* __restrict__ Bs) {
  __shared__ u16 t[64][66];
  int z = blockIdx.z; int b = z / 6, tt = z % 6 + 1;
  int zE = b * 7 + tt;
  int er0 = blockIdx.x * 64, ec0 = blockIdx.y * 64;
  const u16* e = E + ((size_t)zE << 20);
  int tid = threadIdx.x;
  int ri = tid >> 4, c4 = (tid & 15) * 4;
  #pragma unroll
  for (int p = 0; p < 4; ++p) {
    ushort4 v = *(const ushort4*)(e + (size_t)(er0 + ri + p * 16) * 1024 + ec0 + c4);
    t[ri + p * 16][c4 + 0] = v.x; t[ri + p * 16][c4 + 1] = v.y;
    t[ri + p * 16][c4 + 2] = v.z; t[ri + p * 16][c4 + 3] = v.w;
  }
  __syncthreads();
  size_t outBase = (size_t)(b * 6 + tt - 1) << 20;
  float ir0 = 1.f / rsum[zE * 1024 + er0 + c4 + 0];
  float ir1 = 1.f / rsum[zE * 1024 + er0 + c4 + 1];
  float ir2 = 1.f / rsum[zE * 1024 + er0 + c4 + 2];
  float ir3 = 1.f / rsum[zE * 1024 + er0 + c4 + 3];
  #pragma unroll
  for (int p = 0; p < 4; ++p) {
    int roL = ri + p * 16;
    int ro = ec0 + roL;
    float ic = 1.f / csum[zE * 1024 + ro];
    float v0 = bf2f(t[c4 + 0][roL]), v1 = bf2f(t[c4 + 1][roL]);
    float v2 = bf2f(t[c4 + 2][roL]), v3 = bf2f(t[c4 + 3][roL]);
    ushort4 op, os;
    op.x = f2bf(v0 * ir0); op.y = f2bf(v1 * ir1); op.z = f2bf(v2 * ir2); op.w = f2bf(v3 * ir3);
    os.x = f2bf(v0 * ic);  os.y = f2bf(v1 * ic);  os.z = f2bf(v2 * ic);  os.w = f2bf(v3 * ic);
    size_t off = outBase + (size_t)ro * 1024 + er0 + c4;
    *(ushort4*)(Bp + off) = op;
    *(ushort4*)(Bs + off) = os;
  }
}

// ---------------- generic NT GEMM, bf16 in, 128x128 tile, BK=64, double-buffered ----------------
struct GemmBatch { const u16* A[24]; const u16* B[24]; u16* C[8]; };
enum { M_HEAD = 0, M_EXP = 1, M_PLAIN = 2, M_AAR = 3 };

__device__ __forceinline__ void stage_tile(const u16* __restrict__ g, int ld, int r0, int k0, u16* lds) {
  int tid = threadIdx.x;
  int lane = tid & 63, wv = tid >> 6;
  #pragma unroll
  for (int j = 0; j < 4; ++j) {
    int gi = ((wv << 2) + j) * 64 + lane;   // 16B granule index
    int row = gi >> 3;
    int wp = (gi & 7) << 4;                 // physical byte in 128B row
    int lc = wp ^ ((row & 7) << 4);         // logical byte (inverse swizzle on source)
    const u16* src = g + (size_t)(r0 + row) * ld + k0 + (lc >> 1);
    gload16(src, lds + ((wv << 2) + j) * 512);
  }
}

__device__ __forceinline__ short8 frag_ld(const u16* s, int row, int kb) {
  int off = row * 128 + (kb ^ ((row & 7) << 4));
  return *(const short8*)((const char*)s + off);
}

template <int MODE>
__global__ __launch_bounds__(256) void gemm_nt(const u16* __restrict__ gA, const u16* __restrict__ gB,
                                               u16* __restrict__ gC, GemmBatch batch,
                                               const float* __restrict__ bias,
                                               float* __restrict__ rowsumR, u64* __restrict__ amax,
                                               float* __restrict__ diagv,
                                               float* __restrict__ rsumE, float* __restrict__ csumE) {
  __shared__ u16 As[2][128 * 64];
  __shared__ u16 Bs[2][128 * 64];
  int tid = threadIdx.x, lane = tid & 63, wv = tid >> 6;
  int wr = wv >> 1, wc = wv & 1;
  int z = blockIdx.z;
  const u16 *A, *B; u16* C;
  int K, lda, ldb, ldc;
  if constexpr (MODE == M_HEAD) {
    A = gA; B = gB; C = gC; K = 512; lda = 512; ldb = 512; ldc = 128;
  } else if constexpr (MODE == M_EXP) {
    int b = z / 7, t = z % 7;
    size_t offA = (size_t)(b * 8 + t) * 131072;
    A = gA + offA; B = gA + offA + 131072; C = gC + ((size_t)z << 20);
    K = 128; lda = 128; ldb = 128; ldc = 1024;
  } else if constexpr (MODE == M_PLAIN) {
    A = batch.A[z]; B = batch.B[z]; C = batch.C[z];
    K = 1024; lda = 1024; ldb = 1024; ldc = 1024;
  } else {
    A = batch.A[z]; B = batch.B[z]; C = nullptr;
    K = 1024; lda = 1024; ldb = 1024; ldc = 1024;
  }
  int m0 = blockIdx.x * 128, n0 = blockIdx.y * 128;

  f32x4 acc[4][4] = {};
  int nt = K >> 6;

  stage_tile(A, lda, m0, 0, As[0]);
  stage_tile(B, ldb, n0, 0, Bs[0]);
  __syncthreads();

  for (int kt = 0; kt < nt; ++kt) {
    int cur = kt & 1;
    if (kt + 1 < nt) {
      stage_tile(A, lda, m0, (kt + 1) << 6, As[cur ^ 1]);
      stage_tile(B, ldb, n0, (kt + 1) << 6, Bs[cur ^ 1]);
    }
    const u16* Ac = As[cur];
    const u16* Bc = Bs[cur];
    #pragma unroll
    for (int ks = 0; ks < 2; ++ks) {
      short8 af[4], bfv[4];
      #pragma unroll
      for (int f = 0; f < 4; ++f) {
        af[f]  = frag_ld(Ac, (wr << 6) + (f << 4) + (lane & 15), (ks << 6) + ((lane >> 4) << 4));
        bfv[f] = frag_ld(Bc, (wc << 6) + (f << 4) + (lane & 15), (ks << 6) + ((lane >> 4) << 4));
      }
      #pragma unroll
      for (int fr = 0; fr < 4; ++fr)
        #pragma unroll
        for (int fc = 0; fc < 4; ++fc)
          acc[fr][fc] = __builtin_amdgcn_mfma_f32_16x16x32_bf16(af[fr], bfv[fc], acc[fr][fc], 0, 0, 0);
    }
    __syncthreads();
  }

  if constexpr (MODE == M_AAR) {
    #pragma unroll
    for (int fr = 0; fr < 4; ++fr) {
      #pragma unroll
      for (int j = 0; j < 4; ++j) {
        float rs = 0.f, mv = -1.f; int mc = 0;
        #pragma unroll
        for (int fc = 0; fc < 4; ++fc) {
          float v = acc[fr][fc][j];
          rs += v;
          int c = n0 + (wc << 6) + (fc << 4) + (lane & 15);
          if (v > mv) { mv = v; mc = c; }
        }
        u64 pk = ((u64)__float_as_uint(mv) << 32) | (u64)(unsigned)(1023 - mc);
        #pragma unroll
        for (int m = 1; m < 16; m <<= 1) {
          rs += __shfl_xor(rs, m, 64);
          u64 o = __shfl_xor(pk, m, 64);
          pk = (o > pk) ? o : pk;
        }
        if ((lane & 15) == 0) {
          int row = m0 + (wr << 6) + (fr << 4) + ((lane >> 4) << 2) + j;
          atomicAdd(&rowsumR[(z << 10) + row], rs);
          atomicMax(&amax[(z << 10) + row], pk);
        }
      }
      if (m0 == n0 && wr == wc) {
        int jj = (lane & 15) - ((lane >> 4) << 2);
        if (jj >= 0 && jj < 4) {
          int row = m0 + (wr << 6) + (fr << 4) + (lane & 15);
          float dv = (jj == 0) ? acc[fr][fr][0] : (jj == 1) ? acc[fr][fr][1]
                    : (jj == 2) ? acc[fr][fr][2] : acc[fr][fr][3];
          diagv[(z << 10) + row] = dv;
        }
      }
    }
  } else if constexpr (MODE == M_EXP) {
    float rp[4][4] = {};
    float cp[4] = {};
    #pragma unroll
    for (int fr = 0; fr < 4; ++fr)
      #pragma unroll
      for (int fc = 0; fc < 4; ++fc)
        #pragma unroll
        for (int j = 0; j < 4; ++j) {
          int row = m0 + (wr << 6) + (fr << 4) + ((lane >> 4) << 2) + j;
          int col = n0 + (wc << 6) + (fc << 4) + (lane & 15);
          float v = exp2f(acc[fr][fc][j] * KEXP);
          C[(size_t)row * ldc + col] = f2bf(v);
          rp[fr][j] += v;
          cp[fc] += v;
        }
    #pragma unroll
    for (int fr = 0; fr < 4; ++fr)
      #pragma unroll
      for (int j = 0; j < 4; ++j) {
        float r = rp[fr][j];
        r += __shfl_xor(r, 1, 64); r += __shfl_xor(r, 2, 64);
        r += __shfl_xor(r, 4, 64); r += __shfl_xor(r, 8, 64);
        if ((lane & 15) == 0) {
          int row = m0 + (wr << 6) + (fr << 4) + ((lane >> 4) << 2) + j;
          atomicAdd(&rsumE[z * 1024 + row], r);
        }
      }
    #pragma unroll
    for (int fc = 0; fc < 4; ++fc) {
      float c = cp[fc];
      c += __shfl_xor(c, 16, 64); c += __shfl_xor(c, 32, 64);
      if ((lane >> 4) == 0) {
        int col = n0 + (wc << 6) + (fc << 4) + (lane & 15);
        atomicAdd(&csumE[z * 1024 + col], c);
      }
    }
  } else {
    #pragma unroll
    for (int fr = 0; fr < 4; ++fr)
      #pragma unroll
      for (int fc = 0; fc < 4; ++fc)
        #pragma unroll
        for (int j = 0; j < 4; ++j) {
          int row = m0 + (wr << 6) + (fr << 4) + ((lane >> 4) << 2) + j;
          int col = n0 + (wc << 6) + (fc << 4) + (lane & 15);
          float v = acc[fr][fc][j];
          if constexpr (MODE == M_HEAD) v += bias[col];
          C[(size_t)row * ldc + col] = f2bf(v);
        }
  }
}

// ---------------- finalize: loss + acc for all 6 walks ----------------
__global__ __launch_bounds__(256) void finalize_k(const float* __restrict__ rowsumR, const u64* __restrict__ amax,
                                                  const float* __restrict__ diagv, float* __restrict__ out) {
  __shared__ float sl[256], sa[256];
  int w = blockIdx.x;  // 0..5
  int tid = threadIdx.x;
  float ls = 0.f, ac = 0.f;
  for (int idx = tid; idx < 4096; idx += 256) {
    int zi = (w << 12) + idx;
    int n = idx & 1023;
    float rs = rowsumR[zi];
    float dv = diagv[zi];
    ls += logf(rs + 1024.f * 1e-20f) - logf(dv + 1e-20f);
    unsigned pred = 1023u - (unsigned)(amax[zi] & 0xffffffffULL);
    ac += (pred == (unsigned)n) ? 1.f : 0.f;
  }
  sl[tid] = ls; sa[tid] = ac;
  __syncthreads();
  for (int s2 = 128; s2 > 0; s2 >>= 1) {
    if (tid < s2) { sl[tid] += sl[tid + s2]; sa[tid] += sa[tid + s2]; }
    __syncthreads();
  }
  if (tid == 0) {
    float loss = sl[0] / 4096.f, acv = sa[0] / 4096.f;
    out[1 + w] = loss;
    out[7 + w] = acv;
    if (w == 5) out[0] = loss;
  }
}

extern "C" void kernel_launch(void* const* d_in, const int* in_sizes, int n_in,
                              void* d_out, int out_size, void* d_ws, size_t ws_size,
                              hipStream_t stream) {
  (void)in_sizes; (void)n_in; (void)out_size; (void)ws_size;
  const float* x  = (const float*)d_in[0];
  const float* Wh = (const float*)d_in[1];
  const float* bh = (const float*)d_in[2];
  float* out = (float*)d_out;
  char* ws = (char*)d_ws;
  const size_t MB = 1ull << 20;

  // ---- workspace overlay (209 MB total) ----
  // [0,32)   xT during head GEMM; later P1..P4 (8 MB each)
  // [32,40)  keys
  // [40,41)  Wt(128K) | rsumE(112K) csumE(112K) rowsumR(96K) amax(192K) diagv(96K)
  // [41,97)  E during affinity/k3; later P5 P6 S1 S2 S3 S4 S5
  // [97,105) P0; later S6
  // [105,113) S0
  // [113,161) Bp   (xT-era: free until k3_tr)
  // [161,209) Bs
  u16* xT   = (u16*)(ws);
  u16* keys = (u16*)(ws + 32 * MB);
  u16* Wt   = (u16*)(ws + 40 * MB);
  float* rsumE   = (float*)(ws + 40 * MB + 128 * 1024);
  float* csumE   = (float*)(ws + 40 * MB + 240 * 1024);
  float* rowsumR = (float*)(ws + 40 * MB + 352 * 1024);
  u64*   amax    = (u64*)(ws + 40 * MB + 448 * 1024);
  float* diagv   = (float*)(ws + 40 * MB + 640 * 1024);
  u16* E    = (u16*)(ws + 41 * MB);
  u16* Bp   = (u16*)(ws + 113 * MB);
  u16* Bs   = (u16*)(ws + 161 * MB);

  u16* Pb[7] = { (u16*)(ws + 97 * MB), (u16*)(ws + 0 * MB), (u16*)(ws + 8 * MB),
                 (u16*)(ws + 16 * MB), (u16*)(ws + 24 * MB), (u16*)(ws + 41 * MB),
                 (u16*)(ws + 49 * MB) };
  u16* Sb[7] = { (u16*)(ws + 105 * MB), (u16*)(ws + 57 * MB), (u16*)(ws + 65 * MB),
                 (u16*)(ws + 73 * MB), (u16*)(ws + 81 * MB), (u16*)(ws + 89 * MB),
                 (u16*)(ws + 97 * MB) };

  GemmBatch empty{};

  transpose_x<<<dim3(256, 16, 4), 256, 0, stream>>>(x, xT);
  transpose_w<<<dim3(256), 256, 0, stream>>>(Wh, Wt);
  gemm_nt<M_HEAD><<<dim3(256, 1, 1), 256, 0, stream>>>(xT, Wt, keys, empty, bh,
                                                       nullptr, nullptr, nullptr, nullptr, nullptr);
  normalize_keys<<<dim3(8192), 256, 0, stream>>>(keys);
  // zero rsumE + csumE + rowsumR + amax (contiguous 512 KB)
  (void)hipMemsetAsync(rsumE, 0, 512 * 1024, stream);
  gemm_nt<M_EXP><<<dim3(8, 8, 28), 256, 0, stream>>>(keys, nullptr, E, empty, nullptr,
                                                     nullptr, nullptr, nullptr, rsumE, csumE);
  k3_t0<<<dim3(1024, 1, 4), 256, 0, stream>>>(E, rsumE, csumE, Pb[0], Sb[0]);
  k3_tr<<<dim3(16, 16, 24), 256, 0, stream>>>(E, rsumE, csumE, Bp, Bs);

  for (int i = 1; i <= 6; ++i) {
    GemmBatch gb{};
    for (int b = 0; b < 4; ++b) {
      gb.A[b]     = Pb[i - 1] + (size_t)b * 1048576;
      gb.B[b]     = Bp + (size_t)(b * 6 + i - 1) * 1048576;
      gb.C[b]     = Pb[i] + (size_t)b * 1048576;
      gb.A[4 + b] = Sb[i - 1] + (size_t)b * 1048576;
      gb.B[4 + b] = Bs + (size_t)(b * 6 + i - 1) * 1048576;
      gb.C[4 + b] = Sb[i] + (size_t)b * 1048576;
    }
    gemm_nt<M_PLAIN><<<dim3(8, 8, 8), 256, 0, stream>>>(nullptr, nullptr, nullptr, gb, nullptr,
                                                        nullptr, nullptr, nullptr, nullptr, nullptr);
  }

  GemmBatch ga{};
  for (int i = 1; i <= 6; ++i)
    for (int b = 0; b < 4; ++b) {
      ga.A[(i - 1) * 4 + b] = Pb[i] + (size_t)b * 1048576;
      ga.B[(i - 1) * 4 + b] = Sb[i] + (size_t)b * 1048576;
    }
  gemm_nt<M_AAR><<<dim3(8, 8, 24), 256, 0, stream>>>(nullptr, nullptr, nullptr, ga, nullptr,
                                                     rowsumR, amax, diagv, nullptr, nullptr);
  finalize_k<<<dim3(6), 256, 0, stream>>>(rowsumR, amax, diagv, out);
}

// Round 4
// 369.018 us; speedup vs baseline: 1.2907x; 1.0362x over previous
//
#include <hip/hip_runtime.h>
#include <cstdint>
#include <cstddef>

typedef unsigned short u16;
typedef unsigned long long u64;
using short8 = __attribute__((ext_vector_type(8))) short;
using f32x4  = __attribute__((ext_vector_type(4))) float;

// (1/0.07) * log2(e)
#define KEXP 20.609929155556620f

__device__ __forceinline__ u16 f2bf(float f) {
  unsigned u = __float_as_uint(f);
  u += 0x7fffu + ((u >> 16) & 1u);
  return (u16)(u >> 16);
}
__device__ __forceinline__ float bf2f(u16 h) { return __uint_as_float(((unsigned)h) << 16); }

typedef const unsigned int GASu32 __attribute__((address_space(1)));
typedef unsigned int LASu32 __attribute__((address_space(3)));

__device__ __forceinline__ void gload16(const u16* src, u16* dstLds) {
  __builtin_amdgcn_global_load_lds((GASu32*)src, (LASu32*)dstLds, 16, 0, 0);
}

// ---------------- transpose x: [B][C][S] f32 -> xT [B][S][C] bf16 ----------------
__global__ __launch_bounds__(256) void transpose_x(const float* __restrict__ x, u16* __restrict__ xT) {
  __shared__ float t[32][33];
  int b = blockIdx.z, c0 = blockIdx.y * 32, s0 = blockIdx.x * 32;
  int tid = threadIdx.x;
  int ci = tid >> 3, s4 = (tid & 7) * 4;
  float4 v = *(const float4*)(x + ((size_t)b * 512 + c0 + ci) * 8192 + s0 + s4);
  t[ci][s4 + 0] = v.x; t[ci][s4 + 1] = v.y; t[ci][s4 + 2] = v.z; t[ci][s4 + 3] = v.w;
  __syncthreads();
  int si = tid >> 3, c4 = (tid & 7) * 4;
  ushort4 o;
  o.x = f2bf(t[c4 + 0][si]); o.y = f2bf(t[c4 + 1][si]);
  o.z = f2bf(t[c4 + 2][si]); o.w = f2bf(t[c4 + 3][si]);
  *(ushort4*)(xT + ((size_t)b * 8192 + s0 + si) * 512 + c0 + c4) = o;
}

// ---------------- transpose W: [512][128] f32 -> Wt [128][512] bf16 ----------------
__global__ __launch_bounds__(256) void transpose_w(const float* __restrict__ W, u16* __restrict__ Wt) {
  int idx = blockIdx.x * 256 + threadIdx.x;  // 65536
  int d = idx >> 9, c = idx & 511;
  Wt[idx] = f2bf(W[c * 128 + d]);
}

// ---------------- normalize keys rows (in place, bf16 [32768][128]) ----------------
__global__ __launch_bounds__(256) void normalize_keys(u16* __restrict__ keys) {
  int wv = threadIdx.x >> 6, lane = threadIdx.x & 63;
  int row = blockIdx.x * 4 + wv;
  unsigned* p = (unsigned*)(keys + (size_t)row * 128) + lane;
  unsigned v = *p;
  float a = bf2f((u16)(v & 0xffffu)), b = bf2f((u16)(v >> 16));
  float s = a * a + b * b;
  #pragma unroll
  for (int m = 1; m < 64; m <<= 1) s += __shfl_xor(s, m, 64);
  float sc = 1.f / fmaxf(sqrtf(s), 1e-12f);
  *p = (unsigned)f2bf(a * sc) | ((unsigned)f2bf(b * sc) << 16);
}

// ---------------- t=0: P0 = row-normalized E0, S0 = col-normalized E0 ----------------
__global__ __launch_bounds__(256) void k3_t0(const u16* __restrict__ E, const float* __restrict__ rsum,
                                             const float* __restrict__ csum,
                                             u16* __restrict__ P0, u16* __restrict__ S0) {
  int b = blockIdx.z, r = blockIdx.x;
  int zE = b * 7;
  const u16* e = E + ((size_t)zE << 20) + (size_t)r * 1024;
  float rr = 1.f / rsum[zE * 1024 + r];
  int c = threadIdx.x * 4;
  ushort4 v = *(const ushort4*)(e + c);
  float4 cv = *(const float4*)(csum + zE * 1024 + c);
  ushort4 o1, o2;
  float v0 = bf2f(v.x), v1 = bf2f(v.y), v2 = bf2f(v.z), v3 = bf2f(v.w);
  o1.x = f2bf(v0 * rr); o1.y = f2bf(v1 * rr); o1.z = f2bf(v2 * rr); o1.w = f2bf(v3 * rr);
  o2.x = f2bf(v0 / cv.x); o2.y = f2bf(v1 / cv.y); o2.z = f2bf(v2 / cv.z); o2.w = f2bf(v3 / cv.w);
  size_t base = ((size_t)b << 20) + (size_t)r * 1024 + c;
  *(ushort4*)(P0 + base) = o1;
  *(ushort4*)(S0 + base) = o2;
}

// ---------------- t>=1: Bp[t][n][k] = E[k][n]/rowsum[k], Bs[t][n][k] = E[k][n]/colsum[n] ----------------
__global__ __launch_bounds__(256) void k3_tr(const u16* __restrict__ E, const float* __restrict__ rsum,
                                             const float* __restrict__ csum,
                                             u16* __restrict__ Bp, u16* __restrict__ Bs) {
  __shared__ u16 t[64][66];
  int z = blockIdx.z; int b = z / 6, tt = z % 6 + 1;
  int zE = b * 7 + tt;
  int er0 = blockIdx.x * 64, ec0 = blockIdx.y * 64;
  const u16* e = E + ((size_t)zE << 20);
  int tid = threadIdx.x;
  int ri = tid >> 4, c4 = (tid & 15) * 4;
  #pragma unroll
  for (int p = 0; p < 4; ++p) {
    ushort4 v = *(const ushort4*)(e + (size_t)(er0 + ri + p * 16) * 1024 + ec0 + c4);
    t[ri + p * 16][c4 + 0] = v.x; t[ri + p * 16][c4 + 1] = v.y;
    t[ri + p * 16][c4 + 2] = v.z; t[ri + p * 16][c4 + 3] = v.w;
  }
  __syncthreads();
  size_t outBase = (size_t)(b * 6 + tt - 1) << 20;
  float ir0 = 1.f / rsum[zE * 1024 + er0 + c4 + 0];
  float ir1 = 1.f / rsum[zE * 1024 + er0 + c4 + 1];
  float ir2 = 1.f / rsum[zE * 1024 + er0 + c4 + 2];
  float ir3 = 1.f / rsum[zE * 1024 + er0 + c4 + 3];
  #pragma unroll
  for (int p = 0; p < 4; ++p) {
    int roL = ri + p * 16;
    int ro = ec0 + roL;
    float ic = 1.f / csum[zE * 1024 + ro];
    float v0 = bf2f(t[c4 + 0][roL]), v1 = bf2f(t[c4 + 1][roL]);
    float v2 = bf2f(t[c4 + 2][roL]), v3 = bf2f(t[c4 + 3][roL]);
    ushort4 op, os;
    op.x = f2bf(v0 * ir0); op.y = f2bf(v1 * ir1); op.z = f2bf(v2 * ir2); op.w = f2bf(v3 * ir3);
    os.x = f2bf(v0 * ic);  os.y = f2bf(v1 * ic);  os.z = f2bf(v2 * ic);  os.w = f2bf(v3 * ic);
    size_t off = outBase + (size_t)ro * 1024 + er0 + c4;
    *(ushort4*)(Bp + off) = op;
    *(ushort4*)(Bs + off) = os;
  }
}

// ---------------- generic NT GEMM, bf16 in, 128x128 tile, BK=32, 3-buffer ring ----------------
// LDS tile layout: 64 physical rows x 128B; 2 logical matrix rows per LDS row.
// logical (r, kbyte): rp=r>>1, slot_lin = ((r&1)<<2)|(kbyte>>4), slot = slot_lin ^ (rp&7)
// byte off = rp*128 + slot*16.  Wave frag read -> 2 lanes/bank-quad (free).
struct GemmBatch { const u16* A[24]; const u16* B[24]; u16* C[8]; };
enum { M_HEAD = 0, M_EXP = 1, M_PLAIN = 2, M_AAR = 3 };

__device__ __forceinline__ int lds_off32(int r, int kbyte) {
  int rp = r >> 1;
  int sl = (((r & 1) << 2) | (kbyte >> 4)) ^ (rp & 7);
  return rp * 128 + sl * 16;
}

// stage one 128x32 bf16 tile (8KB) into LDS: linear dest, inverse-swizzled source.
// per thread: 2 global_load_lds of 16B.
__device__ __forceinline__ void stage_tile32(const u16* __restrict__ g, int ld, int r0, int k0, u16* lds) {
  int tid = threadIdx.x;
  #pragma unroll
  for (int j = 0; j < 2; ++j) {
    int gidx = j * 256 + tid;          // granule 0..511
    int rp = gidx >> 3, slot = gidx & 7;
    int sp = slot ^ (rp & 7);
    int r = (rp << 1) | (sp >> 2);
    int kb16 = sp & 3;
    const u16* src = g + (size_t)(r0 + r) * ld + k0 + kb16 * 8;
    gload16(src, lds + gidx * 8);
  }
}

__device__ __forceinline__ short8 frag_ld32(const u16* s, int row, int kbyte) {
  return *(const short8*)((const char*)s + lds_off32(row, kbyte));
}

template <int MODE>
__global__ __launch_bounds__(256) void gemm_nt(const u16* __restrict__ gA, const u16* __restrict__ gB,
                                               u16* __restrict__ gC, GemmBatch batch,
                                               const float* __restrict__ bias,
                                               float* __restrict__ rowsumR, u64* __restrict__ amax,
                                               float* __restrict__ diagv,
                                               float* __restrict__ rsumE, float* __restrict__ csumE) {
  __shared__ u16 As[3][4096];   // 3 x 8KB
  __shared__ u16 Bs[3][4096];
  int tid = threadIdx.x, lane = tid & 63, wv = tid >> 6;
  int wr = wv >> 1, wc = wv & 1;
  int z = blockIdx.z;
  const u16 *A, *B; u16* C;
  int K, lda, ldb, ldc;
  if constexpr (MODE == M_HEAD) {
    A = gA; B = gB; C = gC; K = 512; lda = 512; ldb = 512; ldc = 128;
  } else if constexpr (MODE == M_EXP) {
    int b = z / 7, t = z % 7;
    size_t offA = (size_t)(b * 8 + t) * 131072;
    A = gA + offA; B = gA + offA + 131072; C = gC + ((size_t)z << 20);
    K = 128; lda = 128; ldb = 128; ldc = 1024;
  } else if constexpr (MODE == M_PLAIN) {
    A = batch.A[z]; B = batch.B[z]; C = batch.C[z];
    K = 1024; lda = 1024; ldb = 1024; ldc = 1024;
  } else {
    A = batch.A[z]; B = batch.B[z]; C = nullptr;
    K = 1024; lda = 1024; ldb = 1024; ldc = 1024;
  }
  int m0 = blockIdx.x * 128, n0 = blockIdx.y * 128;

  f32x4 acc[4][4] = {};
  int nt = K >> 5;               // BK=32; all modes have nt >= 4

  // prologue: stage tiles 0,1,2 (12 vmem instrs per thread in flight)
  stage_tile32(A, lda, m0, 0,  As[0]); stage_tile32(B, ldb, n0, 0,  Bs[0]);
  stage_tile32(A, lda, m0, 32, As[1]); stage_tile32(B, ldb, n0, 32, Bs[1]);
  stage_tile32(A, lda, m0, 64, As[2]); stage_tile32(B, ldb, n0, 64, Bs[2]);

  for (int t = 0; t < nt; ++t) {
    int rem = nt - 1 - t;        // fully-staged tiles beyond t: min(rem,2), 4 instr each
    if (rem >= 2)      asm volatile("s_waitcnt vmcnt(8)" ::: "memory");
    else if (rem == 1) asm volatile("s_waitcnt vmcnt(4)" ::: "memory");
    else               asm volatile("s_waitcnt vmcnt(0)" ::: "memory");
    __builtin_amdgcn_s_barrier();            // everyone's tile-t loads landed
    __builtin_amdgcn_sched_barrier(0);
    const u16* Ac = As[t % 3];
    const u16* Bc = Bs[t % 3];
    short8 af[4], bfv[4];
    #pragma unroll
    for (int f = 0; f < 4; ++f) {
      af[f]  = frag_ld32(Ac, (wr << 6) + (f << 4) + (lane & 15), (lane >> 4) << 4);
      bfv[f] = frag_ld32(Bc, (wc << 6) + (f << 4) + (lane & 15), (lane >> 4) << 4);
    }
    #pragma unroll
    for (int fr = 0; fr < 4; ++fr)
      #pragma unroll
      for (int fc = 0; fc < 4; ++fc)
        acc[fr][fc] = __builtin_amdgcn_mfma_f32_16x16x32_bf16(af[fr], bfv[fc], acc[fr][fc], 0, 0, 0);
    __builtin_amdgcn_sched_barrier(0);
    __builtin_amdgcn_s_barrier();            // everyone done reading slot t%3
    if (t + 3 < nt) {                        // refill the slot just vacated
      stage_tile32(A, lda, m0, (t + 3) << 5, As[t % 3]);
      stage_tile32(B, ldb, n0, (t + 3) << 5, Bs[t % 3]);
    }
  }

  if constexpr (MODE == M_AAR) {
    #pragma unroll
    for (int fr = 0; fr < 4; ++fr) {
      #pragma unroll
      for (int j = 0; j < 4; ++j) {
        float rs = 0.f, mv = -1.f; int mc = 0;
        #pragma unroll
        for (int fc = 0; fc < 4; ++fc) {
          float v = acc[fr][fc][j];
          rs += v;
          int c = n0 + (wc << 6) + (fc << 4) + (lane & 15);
          if (v > mv) { mv = v; mc = c; }
        }
        u64 pk = ((u64)__float_as_uint(mv) << 32) | (u64)(unsigned)(1023 - mc);
        #pragma unroll
        for (int m = 1; m < 16; m <<= 1) {
          rs += __shfl_xor(rs, m, 64);
          u64 o = __shfl_xor(pk, m, 64);
          pk = (o > pk) ? o : pk;
        }
        if ((lane & 15) == 0) {
          int row = m0 + (wr << 6) + (fr << 4) + ((lane >> 4) << 2) + j;
          atomicAdd(&rowsumR[(z << 10) + row], rs);
          atomicMax(&amax[(z << 10) + row], pk);
        }
      }
      if (m0 == n0 && wr == wc) {
        int jj = (lane & 15) - ((lane >> 4) << 2);
        if (jj >= 0 && jj < 4) {
          int row = m0 + (wr << 6) + (fr << 4) + (lane & 15);
          float dv = (jj == 0) ? acc[fr][fr][0] : (jj == 1) ? acc[fr][fr][1]
                    : (jj == 2) ? acc[fr][fr][2] : acc[fr][fr][3];
          diagv[(z << 10) + row] = dv;
        }
      }
    }
  } else if constexpr (MODE == M_EXP) {
    float rp[4][4] = {};
    float cp[4] = {};
    #pragma unroll
    for (int fr = 0; fr < 4; ++fr)
      #pragma unroll
      for (int fc = 0; fc < 4; ++fc)
        #pragma unroll
        for (int j = 0; j < 4; ++j) {
          int row = m0 + (wr << 6) + (fr << 4) + ((lane >> 4) << 2) + j;
          int col = n0 + (wc << 6) + (fc << 4) + (lane & 15);
          float v = exp2f(acc[fr][fc][j] * KEXP);
          C[(size_t)row * ldc + col] = f2bf(v);
          rp[fr][j] += v;
          cp[fc] += v;
        }
    #pragma unroll
    for (int fr = 0; fr < 4; ++fr)
      #pragma unroll
      for (int j = 0; j < 4; ++j) {
        float r = rp[fr][j];
        r += __shfl_xor(r, 1, 64); r += __shfl_xor(r, 2, 64);
        r += __shfl_xor(r, 4, 64); r += __shfl_xor(r, 8, 64);
        if ((lane & 15) == 0) {
          int row = m0 + (wr << 6) + (fr << 4) + ((lane >> 4) << 2) + j;
          atomicAdd(&rsumE[z * 1024 + row], r);
        }
      }
    #pragma unroll
    for (int fc = 0; fc < 4; ++fc) {
      float c = cp[fc];
      c += __shfl_xor(c, 16, 64); c += __shfl_xor(c, 32, 64);
      if ((lane >> 4) == 0) {
        int col = n0 + (wc << 6) + (fc << 4) + (lane & 15);
        atomicAdd(&csumE[z * 1024 + col], c);
      }
    }
  } else {
    #pragma unroll
    for (int fr = 0; fr < 4; ++fr)
      #pragma unroll
      for (int fc = 0; fc < 4; ++fc)
        #pragma unroll
        for (int j = 0; j < 4; ++j) {
          int row = m0 + (wr << 6) + (fr << 4) + ((lane >> 4) << 2) + j;
          int col = n0 + (wc << 6) + (fc << 4) + (lane & 15);
          float v = acc[fr][fc][j];
          if constexpr (MODE == M_HEAD) v += bias[col];
          C[(size_t)row * ldc + col] = f2bf(v);
        }
  }
}

// ---------------- finalize: loss + acc for all 6 walks ----------------
__global__ __launch_bounds__(256) void finalize_k(const float* __restrict__ rowsumR, const u64* __restrict__ amax,
                                                  const float* __restrict__ diagv, float* __restrict__ out) {
  __shared__ float sl[256], sa[256];
  int w = blockIdx.x;  // 0..5
  int tid = threadIdx.x;
  float ls = 0.f, ac = 0.f;
  for (int idx = tid; idx < 4096; idx += 256) {
    int zi = (w << 12) + idx;
    int n = idx & 1023;
    float rs = rowsumR[zi];
    float dv = diagv[zi];
    ls += logf(rs + 1024.f * 1e-20f) - logf(dv + 1e-20f);
    unsigned pred = 1023u - (unsigned)(amax[zi] & 0xffffffffULL);
    ac += (pred == (unsigned)n) ? 1.f : 0.f;
  }
  sl[tid] = ls; sa[tid] = ac;
  __syncthreads();
  for (int s2 = 128; s2 > 0; s2 >>= 1) {
    if (tid < s2) { sl[tid] += sl[tid + s2]; sa[tid] += sa[tid + s2]; }
    __syncthreads();
  }
  if (tid == 0) {
    float loss = sl[0] / 4096.f, acv = sa[0] / 4096.f;
    out[1 + w] = loss;
    out[7 + w] = acv;
    if (w == 5) out[0] = loss;
  }
}

extern "C" void kernel_launch(void* const* d_in, const int* in_sizes, int n_in,
                              void* d_out, int out_size, void* d_ws, size_t ws_size,
                              hipStream_t stream) {
  (void)in_sizes; (void)n_in; (void)out_size; (void)ws_size;
  const float* x  = (const float*)d_in[0];
  const float* Wh = (const float*)d_in[1];
  const float* bh = (const float*)d_in[2];
  float* out = (float*)d_out;
  char* ws = (char*)d_ws;
  const size_t MB = 1ull << 20;

  // ---- workspace overlay (209 MB total) ----
  u16* xT   = (u16*)(ws);
  u16* keys = (u16*)(ws + 32 * MB);
  u16* Wt   = (u16*)(ws + 40 * MB);
  float* rsumE   = (float*)(ws + 40 * MB + 128 * 1024);
  float* csumE   = (float*)(ws + 40 * MB + 240 * 1024);
  float* rowsumR = (float*)(ws + 40 * MB + 352 * 1024);
  u64*   amax    = (u64*)(ws + 40 * MB + 448 * 1024);
  float* diagv   = (float*)(ws + 40 * MB + 640 * 1024);
  u16* E    = (u16*)(ws + 41 * MB);
  u16* Bp   = (u16*)(ws + 113 * MB);
  u16* Bs   = (u16*)(ws + 161 * MB);

  u16* Pb[7] = { (u16*)(ws + 97 * MB), (u16*)(ws + 0 * MB), (u16*)(ws + 8 * MB),
                 (u16*)(ws + 16 * MB), (u16*)(ws + 24 * MB), (u16*)(ws + 41 * MB),
                 (u16*)(ws + 49 * MB) };
  u16* Sb[7] = { (u16*)(ws + 105 * MB), (u16*)(ws + 57 * MB), (u16*)(ws + 65 * MB),
                 (u16*)(ws + 73 * MB), (u16*)(ws + 81 * MB), (u16*)(ws + 89 * MB),
                 (u16*)(ws + 97 * MB) };

  GemmBatch empty{};

  transpose_x<<<dim3(256, 16, 4), 256, 0, stream>>>(x, xT);
  transpose_w<<<dim3(256), 256, 0, stream>>>(Wh, Wt);
  gemm_nt<M_HEAD><<<dim3(256, 1, 1), 256, 0, stream>>>(xT, Wt, keys, empty, bh,
                                                       nullptr, nullptr, nullptr, nullptr, nullptr);
  normalize_keys<<<dim3(8192), 256, 0, stream>>>(keys);
  (void)hipMemsetAsync(rsumE, 0, 512 * 1024, stream);
  gemm_nt<M_EXP><<<dim3(8, 8, 28), 256, 0, stream>>>(keys, nullptr, E, empty, nullptr,
                                                     nullptr, nullptr, nullptr, rsumE, csumE);
  k3_t0<<<dim3(1024, 1, 4), 256, 0, stream>>>(E, rsumE, csumE, Pb[0], Sb[0]);
  k3_tr<<<dim3(16, 16, 24), 256, 0, stream>>>(E, rsumE, csumE, Bp, Bs);

  for (int i = 1; i <= 6; ++i) {
    GemmBatch gb{};
    for (int b = 0; b < 4; ++b) {
      gb.A[b]     = Pb[i - 1] + (size_t)b * 1048576;
      gb.B[b]     = Bp + (size_t)(b * 6 + i - 1) * 1048576;
      gb.C[b]     = Pb[i] + (size_t)b * 1048576;
      gb.A[4 + b] = Sb[i - 1] + (size_t)b * 1048576;
      gb.B[4 + b] = Bs + (size_t)(b * 6 + i - 1) * 1048576;
      gb.C[4 + b] = Sb[i] + (size_t)b * 1048576;
    }
    gemm_nt<M_PLAIN><<<dim3(8, 8, 8), 256, 0, stream>>>(nullptr, nullptr, nullptr, gb, nullptr,
                                                        nullptr, nullptr, nullptr, nullptr, nullptr);
  }

  GemmBatch ga{};
  for (int i = 1; i <= 6; ++i)
    for (int b = 0; b < 4; ++b) {
      ga.A[(i - 1) * 4 + b] = Pb[i] + (size_t)b * 1048576;
      ga.B[(i - 1) * 4 + b] = Sb[i] + (size_t)b * 1048576;
    }
  gemm_nt<M_AAR><<<dim3(8, 8, 24), 256, 0, stream>>>(nullptr, nullptr, nullptr, ga, nullptr,
                                                     rowsumR, amax, diagv, nullptr, nullptr);
  finalize_k<<<dim3(6), 256, 0, stream>>>(rowsumR, amax, diagv, out);
}

// Round 5
// 314.678 us; speedup vs baseline: 1.5135x; 1.1727x over previous
//
#include <hip/hip_runtime.h>
#include <cstdint>
#include <cstddef>

typedef unsigned short u16;
typedef unsigned long long u64;
using short8 = __attribute__((ext_vector_type(8))) short;
using f32x4  = __attribute__((ext_vector_type(4))) float;

// (1/0.07) * log2(e)
#define KEXP 20.609929155556620f

__device__ __forceinline__ u16 f2bf(float f) {
  unsigned u = __float_as_uint(f);
  u += 0x7fffu + ((u >> 16) & 1u);
  return (u16)(u >> 16);
}
__device__ __forceinline__ float bf2f(u16 h) { return __uint_as_float(((unsigned)h) << 16); }

typedef const unsigned int GASu32 __attribute__((address_space(1)));
typedef unsigned int LASu32 __attribute__((address_space(3)));

__device__ __forceinline__ void gload16(const u16* src, u16* dstLds) {
  __builtin_amdgcn_global_load_lds((GASu32*)src, (LASu32*)dstLds, 16, 0, 0);
}

// ---------------- transpose x: [B][C][S] f32 -> xT [B][S][C] bf16 ----------------
__global__ __launch_bounds__(256) void transpose_x(const float* __restrict__ x, u16* __restrict__ xT) {
  __shared__ float t[32][33];
  int b = blockIdx.z, c0 = blockIdx.y * 32, s0 = blockIdx.x * 32;
  int tid = threadIdx.x;
  int ci = tid >> 3, s4 = (tid & 7) * 4;
  float4 v = *(const float4*)(x + ((size_t)b * 512 + c0 + ci) * 8192 + s0 + s4);
  t[ci][s4 + 0] = v.x; t[ci][s4 + 1] = v.y; t[ci][s4 + 2] = v.z; t[ci][s4 + 3] = v.w;
  __syncthreads();
  int si = tid >> 3, c4 = (tid & 7) * 4;
  ushort4 o;
  o.x = f2bf(t[c4 + 0][si]); o.y = f2bf(t[c4 + 1][si]);
  o.z = f2bf(t[c4 + 2][si]); o.w = f2bf(t[c4 + 3][si]);
  *(ushort4*)(xT + ((size_t)b * 8192 + s0 + si) * 512 + c0 + c4) = o;
}

// ---------------- transpose W: [512][128] f32 -> Wt [128][512] bf16 ----------------
__global__ __launch_bounds__(256) void transpose_w(const float* __restrict__ W, u16* __restrict__ Wt) {
  int idx = blockIdx.x * 256 + threadIdx.x;  // 65536
  int d = idx >> 9, c = idx & 511;
  Wt[idx] = f2bf(W[c * 128 + d]);
}

// ---------------- normalize keys rows (in place, bf16 [32768][128]) ----------------
__global__ __launch_bounds__(256) void normalize_keys(u16* __restrict__ keys) {
  int wv = threadIdx.x >> 6, lane = threadIdx.x & 63;
  int row = blockIdx.x * 4 + wv;
  unsigned* p = (unsigned*)(keys + (size_t)row * 128) + lane;
  unsigned v = *p;
  float a = bf2f((u16)(v & 0xffffu)), b = bf2f((u16)(v >> 16));
  float s = a * a + b * b;
  #pragma unroll
  for (int m = 1; m < 64; m <<= 1) s += __shfl_xor(s, m, 64);
  float sc = 1.f / fmaxf(sqrtf(s), 1e-12f);
  *p = (unsigned)f2bf(a * sc) | ((unsigned)f2bf(b * sc) << 16);
}

// ---------------- t=0: P0 = row-normalized E0, S0 = col-normalized E0 ----------------
__global__ __launch_bounds__(256) void k3_t0(const u16* __restrict__ E, const float* __restrict__ rsum,
                                             const float* __restrict__ csum,
                                             u16* __restrict__ P0, u16* __restrict__ S0) {
  int b = blockIdx.z, r = blockIdx.x;
  int zE = b * 7;
  const u16* e = E + ((size_t)zE << 20) + (size_t)r * 1024;
  float rr = 1.f / rsum[zE * 1024 + r];
  int c = threadIdx.x * 4;
  ushort4 v = *(const ushort4*)(e + c);
  float4 cv = *(const float4*)(csum + zE * 1024 + c);
  ushort4 o1, o2;
  float v0 = bf2f(v.x), v1 = bf2f(v.y), v2 = bf2f(v.z), v3 = bf2f(v.w);
  o1.x = f2bf(v0 * rr); o1.y = f2bf(v1 * rr); o1.z = f2bf(v2 * rr); o1.w = f2bf(v3 * rr);
  o2.x = f2bf(v0 / cv.x); o2.y = f2bf(v1 / cv.y); o2.z = f2bf(v2 / cv.z); o2.w = f2bf(v3 / cv.w);
  size_t base = ((size_t)b << 20) + (size_t)r * 1024 + c;
  *(ushort4*)(P0 + base) = o1;
  *(ushort4*)(S0 + base) = o2;
}

// ---------------- t>=1: Bp[t][n][k] = E[k][n]/rowsum[k], Bs[t][n][k] = E[k][n]/colsum[n] ----------------
__global__ __launch_bounds__(256) void k3_tr(const u16* __restrict__ E, const float* __restrict__ rsum,
                                             const float* __restrict__ csum,
                                             u16* __restrict__ Bp, u16* __restrict__ Bs) {
  __shared__ u16 t[64][66];
  int z = blockIdx.z; int b = z / 6, tt = z % 6 + 1;
  int zE = b * 7 + tt;
  int er0 = blockIdx.x * 64, ec0 = blockIdx.y * 64;
  const u16* e = E + ((size_t)zE << 20);
  int tid = threadIdx.x;
  int ri = tid >> 4, c4 = (tid & 15) * 4;
  #pragma unroll
  for (int p = 0; p < 4; ++p) {
    ushort4 v = *(const ushort4*)(e + (size_t)(er0 + ri + p * 16) * 1024 + ec0 + c4);
    t[ri + p * 16][c4 + 0] = v.x; t[ri + p * 16][c4 + 1] = v.y;
    t[ri + p * 16][c4 + 2] = v.z; t[ri + p * 16][c4 + 3] = v.w;
  }
  __syncthreads();
  size_t outBase = (size_t)(b * 6 + tt - 1) << 20;
  float ir0 = 1.f / rsum[zE * 1024 + er0 + c4 + 0];
  float ir1 = 1.f / rsum[zE * 1024 + er0 + c4 + 1];
  float ir2 = 1.f / rsum[zE * 1024 + er0 + c4 + 2];
  float ir3 = 1.f / rsum[zE * 1024 + er0 + c4 + 3];
  #pragma unroll
  for (int p = 0; p < 4; ++p) {
    int roL = ri + p * 16;
    int ro = ec0 + roL;
    float ic = 1.f / csum[zE * 1024 + ro];
    float v0 = bf2f(t[c4 + 0][roL]), v1 = bf2f(t[c4 + 1][roL]);
    float v2 = bf2f(t[c4 + 2][roL]), v3 = bf2f(t[c4 + 3][roL]);
    ushort4 op, os;
    op.x = f2bf(v0 * ir0); op.y = f2bf(v1 * ir1); op.z = f2bf(v2 * ir2); op.w = f2bf(v3 * ir3);
    os.x = f2bf(v0 * ic);  os.y = f2bf(v1 * ic);  os.z = f2bf(v2 * ic);  os.w = f2bf(v3 * ic);
    size_t off = outBase + (size_t)ro * 1024 + er0 + c4;
    *(ushort4*)(Bp + off) = op;
    *(ushort4*)(Bs + off) = os;
  }
}

// ---------------- generic NT GEMM, bf16 in, 128x128 tile, BK=32, 4-slot ring, 1 barrier/step ----------------
// LDS tile layout: 64 physical rows x 128B; 2 logical matrix rows per LDS row.
// logical (r, kbyte): rp=r>>1, slot = (((r&1)<<2)|(kbyte>>4)) ^ (rp&7); byte = rp*128 + slot*16.
struct GemmBatch { const u16* A[24]; const u16* B[24]; u16* C[8]; };
enum { M_HEAD = 0, M_EXP = 1, M_PLAIN = 2, M_AAR = 3 };

__device__ __forceinline__ int lds_off32(int r, int kbyte) {
  int rp = r >> 1;
  int sl = (((r & 1) << 2) | (kbyte >> 4)) ^ (rp & 7);
  return rp * 128 + sl * 16;
}

// stage one 128x32 bf16 tile (8KB): linear LDS dest, inverse-swizzled global source.
// per thread: 2 global_load_lds of 16B.
__device__ __forceinline__ void stage_tile32(const u16* __restrict__ g, int ld, int r0, int k0, u16* lds) {
  int tid = threadIdx.x;
  #pragma unroll
  for (int j = 0; j < 2; ++j) {
    int gidx = j * 256 + tid;          // granule 0..511
    int rp = gidx >> 3, slot = gidx & 7;
    int sp = slot ^ (rp & 7);
    int r = (rp << 1) | (sp >> 2);
    int kb16 = sp & 3;
    const u16* src = g + (size_t)(r0 + r) * ld + k0 + kb16 * 8;
    gload16(src, lds + gidx * 8);
  }
}

__device__ __forceinline__ short8 frag_ld32(const u16* s, int row, int kbyte) {
  return *(const short8*)((const char*)s + lds_off32(row, kbyte));
}

// one pipelined K-step: counted vmcnt, single barrier, ds_read next frags + stage t+3,
// counted lgkmcnt(8) (waits only PREVIOUS tile's frags), setprio'd MFMA.
#define GEMM_BODY(T, FA, FB, NA, NB)                                                    \
  {                                                                                     \
    int t_ = (T);                                                                       \
    if (t_ + 1 < nt) {                                                                  \
      if (t_ + 2 < nt) asm volatile("s_waitcnt vmcnt(4)" ::: "memory");                 \
      else             asm volatile("s_waitcnt vmcnt(0)" ::: "memory");                 \
      __builtin_amdgcn_s_barrier();                                                     \
      __builtin_amdgcn_sched_barrier(0);                                                \
      const u16* An_ = As[(t_ + 1) & 3];                                                \
      const u16* Bn_ = Bs[(t_ + 1) & 3];                                                \
      _Pragma("unroll")                                                                 \
      for (int f = 0; f < 4; ++f) {                                                     \
        NA[f] = frag_ld32(An_, (wr << 6) + (f << 4) + l15, kb);                         \
        NB[f] = frag_ld32(Bn_, (wc << 6) + (f << 4) + l15, kb);                         \
      }                                                                                 \
      if (t_ + 3 < nt) {                                                                \
        stage_tile32(A, lda, m0, (t_ + 3) << 5, As[(t_ + 3) & 3]);                      \
        stage_tile32(B, ldb, n0, (t_ + 3) << 5, Bs[(t_ + 3) & 3]);                      \
      }                                                                                 \
      asm volatile("s_waitcnt lgkmcnt(8)" ::: "memory");                                \
    } else {                                                                            \
      asm volatile("s_waitcnt lgkmcnt(0)" ::: "memory");                                \
    }                                                                                   \
    __builtin_amdgcn_sched_barrier(0);                                                  \
    __builtin_amdgcn_s_setprio(1);                                                      \
    _Pragma("unroll")                                                                   \
    for (int fr = 0; fr < 4; ++fr)                                                      \
      _Pragma("unroll")                                                                 \
      for (int fc2 = 0; fc2 < 4; ++fc2)                                                 \
        acc[fr][fc2] = __builtin_amdgcn_mfma_f32_16x16x32_bf16(FA[fr], FB[fc2],         \
                                                               acc[fr][fc2], 0, 0, 0); \
    __builtin_amdgcn_s_setprio(0);                                                      \
  }

template <int MODE>
__global__ __launch_bounds__(256) void gemm_nt(const u16* __restrict__ gA, const u16* __restrict__ gB,
                                               u16* __restrict__ gC, GemmBatch batch,
                                               const float* __restrict__ bias,
                                               float* __restrict__ rowsumR, u64* __restrict__ amax,
                                               float* __restrict__ diagv,
                                               float* __restrict__ rsumE, float* __restrict__ csumE) {
  __shared__ u16 As[4][4096];   // 4 x 8KB
  __shared__ u16 Bs[4][4096];
  int tid = threadIdx.x, lane = tid & 63, wv = tid >> 6;
  int wr = wv >> 1, wc = wv & 1;
  int l15 = lane & 15, kb = (lane >> 4) << 4;

  // XCD-aware swizzle: 8 XCDs, chunk the 1D grid so consecutive work shares an L2.
  int swz;
  { int per = (int)gridDim.x >> 3; int id0 = blockIdx.x; swz = (id0 & 7) * per + (id0 >> 3); }
  int z, m0, n0;
  if constexpr (MODE == M_HEAD) { z = 0; m0 = swz << 7; n0 = 0; }
  else { z = swz >> 6; int r6 = swz & 63; m0 = (r6 & 7) << 7; n0 = (r6 >> 3) << 7; }

  const u16 *A, *B; u16* C;
  int K, lda, ldb, ldc;
  if constexpr (MODE == M_HEAD) {
    A = gA; B = gB; C = gC; K = 512; lda = 512; ldb = 512; ldc = 128;
  } else if constexpr (MODE == M_EXP) {
    int b = z / 7, t = z % 7;
    size_t offA = (size_t)(b * 8 + t) * 131072;
    A = gA + offA; B = gA + offA + 131072; C = gC + ((size_t)z << 20);
    K = 128; lda = 128; ldb = 128; ldc = 1024;
  } else if constexpr (MODE == M_PLAIN) {
    A = batch.A[z]; B = batch.B[z]; C = batch.C[z];
    K = 1024; lda = 1024; ldb = 1024; ldc = 1024;
  } else {
    A = batch.A[z]; B = batch.B[z]; C = nullptr;
    K = 1024; lda = 1024; ldb = 1024; ldc = 1024;
  }

  f32x4 acc[4][4] = {};
  int nt = K >> 5;               // BK=32; nt in {4,16,32} — always even, >= 4

  // prologue: stage tiles 0,1,2; wait tile 0; read its frags
  stage_tile32(A, lda, m0, 0,  As[0]); stage_tile32(B, ldb, n0, 0,  Bs[0]);
  stage_tile32(A, lda, m0, 32, As[1]); stage_tile32(B, ldb, n0, 32, Bs[1]);
  stage_tile32(A, lda, m0, 64, As[2]); stage_tile32(B, ldb, n0, 64, Bs[2]);
  asm volatile("s_waitcnt vmcnt(8)" ::: "memory");
  __builtin_amdgcn_s_barrier();
  __builtin_amdgcn_sched_barrier(0);
  short8 fa0[4], fb0[4], fa1[4], fb1[4];
  #pragma unroll
  for (int f = 0; f < 4; ++f) {
    fa0[f] = frag_ld32(As[0], (wr << 6) + (f << 4) + l15, kb);
    fb0[f] = frag_ld32(Bs[0], (wc << 6) + (f << 4) + l15, kb);
  }

  for (int t = 0; t < nt; t += 2) {
    GEMM_BODY(t,     fa0, fb0, fa1, fb1);
    GEMM_BODY(t + 1, fa1, fb1, fa0, fb0);
  }

  if constexpr (MODE == M_AAR) {
    #pragma unroll
    for (int fr = 0; fr < 4; ++fr) {
      #pragma unroll
      for (int j = 0; j < 4; ++j) {
        float rs = 0.f, mv = -1.f; int mc = 0;
        #pragma unroll
        for (int fc = 0; fc < 4; ++fc) {
          float v = acc[fr][fc][j];
          rs += v;
          int c = n0 + (wc << 6) + (fc << 4) + l15;
          if (v > mv) { mv = v; mc = c; }
        }
        u64 pk = ((u64)__float_as_uint(mv) << 32) | (u64)(unsigned)(1023 - mc);
        #pragma unroll
        for (int m = 1; m < 16; m <<= 1) {
          rs += __shfl_xor(rs, m, 64);
          u64 o = __shfl_xor(pk, m, 64);
          pk = (o > pk) ? o : pk;
        }
        if (l15 == 0) {
          int row = m0 + (wr << 6) + (fr << 4) + ((lane >> 4) << 2) + j;
          atomicAdd(&rowsumR[(z << 10) + row], rs);
          atomicMax(&amax[(z << 10) + row], pk);
        }
      }
      if (m0 == n0 && wr == wc) {
        int jj = l15 - ((lane >> 4) << 2);
        if (jj >= 0 && jj < 4) {
          int row = m0 + (wr << 6) + (fr << 4) + l15;
          float dv = (jj == 0) ? acc[fr][fr][0] : (jj == 1) ? acc[fr][fr][1]
                    : (jj == 2) ? acc[fr][fr][2] : acc[fr][fr][3];
          diagv[(z << 10) + row] = dv;
        }
      }
    }
  } else if constexpr (MODE == M_EXP) {
    float rp[4][4] = {};
    float cp[4] = {};
    #pragma unroll
    for (int fr = 0; fr < 4; ++fr)
      #pragma unroll
      for (int fc = 0; fc < 4; ++fc)
        #pragma unroll
        for (int j = 0; j < 4; ++j) {
          int row = m0 + (wr << 6) + (fr << 4) + ((lane >> 4) << 2) + j;
          int col = n0 + (wc << 6) + (fc << 4) + l15;
          float v = exp2f(acc[fr][fc][j] * KEXP);
          C[(size_t)row * ldc + col] = f2bf(v);
          rp[fr][j] += v;
          cp[fc] += v;
        }
    #pragma unroll
    for (int fr = 0; fr < 4; ++fr)
      #pragma unroll
      for (int j = 0; j < 4; ++j) {
        float r = rp[fr][j];
        r += __shfl_xor(r, 1, 64); r += __shfl_xor(r, 2, 64);
        r += __shfl_xor(r, 4, 64); r += __shfl_xor(r, 8, 64);
        if (l15 == 0) {
          int row = m0 + (wr << 6) + (fr << 4) + ((lane >> 4) << 2) + j;
          atomicAdd(&rsumE[z * 1024 + row], r);
        }
      }
    #pragma unroll
    for (int fc = 0; fc < 4; ++fc) {
      float c = cp[fc];
      c += __shfl_xor(c, 16, 64); c += __shfl_xor(c, 32, 64);
      if ((lane >> 4) == 0) {
        int col = n0 + (wc << 6) + (fc << 4) + l15;
        atomicAdd(&csumE[z * 1024 + col], c);
      }
    }
  } else {
    #pragma unroll
    for (int fr = 0; fr < 4; ++fr)
      #pragma unroll
      for (int fc = 0; fc < 4; ++fc)
        #pragma unroll
        for (int j = 0; j < 4; ++j) {
          int row = m0 + (wr << 6) + (fr << 4) + ((lane >> 4) << 2) + j;
          int col = n0 + (wc << 6) + (fc << 4) + l15;
          float v = acc[fr][fc][j];
          if constexpr (MODE == M_HEAD) v += bias[col];
          C[(size_t)row * ldc + col] = f2bf(v);
        }
  }
}

// ---------------- finalize: loss + acc for all 6 walks ----------------
__global__ __launch_bounds__(256) void finalize_k(const float* __restrict__ rowsumR, const u64* __restrict__ amax,
                                                  const float* __restrict__ diagv, float* __restrict__ out) {
  __shared__ float sl[256], sa[256];
  int w = blockIdx.x;  // 0..5
  int tid = threadIdx.x;
  float ls = 0.f, ac = 0.f;
  for (int idx = tid; idx < 4096; idx += 256) {
    int zi = (w << 12) + idx;
    int n = idx & 1023;
    float rs = rowsumR[zi];
    float dv = diagv[zi];
    ls += logf(rs + 1024.f * 1e-20f) - logf(dv + 1e-20f);
    unsigned pred = 1023u - (unsigned)(amax[zi] & 0xffffffffULL);
    ac += (pred == (unsigned)n) ? 1.f : 0.f;
  }
  sl[tid] = ls; sa[tid] = ac;
  __syncthreads();
  for (int s2 = 128; s2 > 0; s2 >>= 1) {
    if (tid < s2) { sl[tid] += sl[tid + s2]; sa[tid] += sa[tid + s2]; }
    __syncthreads();
  }
  if (tid == 0) {
    float loss = sl[0] / 4096.f, acv = sa[0] / 4096.f;
    out[1 + w] = loss;
    out[7 + w] = acv;
    if (w == 5) out[0] = loss;
  }
}

extern "C" void kernel_launch(void* const* d_in, const int* in_sizes, int n_in,
                              void* d_out, int out_size, void* d_ws, size_t ws_size,
                              hipStream_t stream) {
  (void)in_sizes; (void)n_in; (void)out_size; (void)ws_size;
  const float* x  = (const float*)d_in[0];
  const float* Wh = (const float*)d_in[1];
  const float* bh = (const float*)d_in[2];
  float* out = (float*)d_out;
  char* ws = (char*)d_ws;
  const size_t MB = 1ull << 20;

  // ---- workspace overlay (209 MB total) ----
  u16* xT   = (u16*)(ws);
  u16* keys = (u16*)(ws + 32 * MB);
  u16* Wt   = (u16*)(ws + 40 * MB);
  float* rsumE   = (float*)(ws + 40 * MB + 128 * 1024);
  float* csumE   = (float*)(ws + 40 * MB + 240 * 1024);
  float* rowsumR = (float*)(ws + 40 * MB + 352 * 1024);
  u64*   amax    = (u64*)(ws + 40 * MB + 448 * 1024);
  float* diagv   = (float*)(ws + 40 * MB + 640 * 1024);
  u16* E    = (u16*)(ws + 41 * MB);
  u16* Bp   = (u16*)(ws + 113 * MB);
  u16* Bs   = (u16*)(ws + 161 * MB);

  u16* Pb[7] = { (u16*)(ws + 97 * MB), (u16*)(ws + 0 * MB), (u16*)(ws + 8 * MB),
                 (u16*)(ws + 16 * MB), (u16*)(ws + 24 * MB), (u16*)(ws + 41 * MB),
                 (u16*)(ws + 49 * MB) };
  u16* Sb[7] = { (u16*)(ws + 105 * MB), (u16*)(ws + 57 * MB), (u16*)(ws + 65 * MB),
                 (u16*)(ws + 73 * MB), (u16*)(ws + 81 * MB), (u16*)(ws + 89 * MB),
                 (u16*)(ws + 97 * MB) };

  GemmBatch empty{};

  transpose_x<<<dim3(256, 16, 4), 256, 0, stream>>>(x, xT);
  transpose_w<<<dim3(256), 256, 0, stream>>>(Wh, Wt);
  gemm_nt<M_HEAD><<<dim3(256), 256, 0, stream>>>(xT, Wt, keys, empty, bh,
                                                 nullptr, nullptr, nullptr, nullptr, nullptr);
  normalize_keys<<<dim3(8192), 256, 0, stream>>>(keys);
  (void)hipMemsetAsync(rsumE, 0, 512 * 1024, stream);
  gemm_nt<M_EXP><<<dim3(1792), 256, 0, stream>>>(keys, nullptr, E, empty, nullptr,
                                                 nullptr, nullptr, nullptr, rsumE, csumE);
  k3_t0<<<dim3(1024, 1, 4), 256, 0, stream>>>(E, rsumE, csumE, Pb[0], Sb[0]);
  k3_tr<<<dim3(16, 16, 24), 256, 0, stream>>>(E, rsumE, csumE, Bp, Bs);

  for (int i = 1; i <= 6; ++i) {
    GemmBatch gb{};
    for (int b = 0; b < 4; ++b) {
      gb.A[b]     = Pb[i - 1] + (size_t)b * 1048576;
      gb.B[b]     = Bp + (size_t)(b * 6 + i - 1) * 1048576;
      gb.C[b]     = Pb[i] + (size_t)b * 1048576;
      gb.A[4 + b] = Sb[i - 1] + (size_t)b * 1048576;
      gb.B[4 + b] = Bs + (size_t)(b * 6 + i - 1) * 1048576;
      gb.C[4 + b] = Sb[i] + (size_t)b * 1048576;
    }
    gemm_nt<M_PLAIN><<<dim3(512), 256, 0, stream>>>(nullptr, nullptr, nullptr, gb, nullptr,
                                                    nullptr, nullptr, nullptr, nullptr, nullptr);
  }

  GemmBatch ga{};
  for (int i = 1; i <= 6; ++i)
    for (int b = 0; b < 4; ++b) {
      ga.A[(i - 1) * 4 + b] = Pb[i] + (size_t)b * 1048576;
      ga.B[(i - 1) * 4 + b] = Sb[i] + (size_t)b * 1048576;
    }
  gemm_nt<M_AAR><<<dim3(1536), 256, 0, stream>>>(nullptr, nullptr, nullptr, ga, nullptr,
                                                 rowsumR, amax, diagv, nullptr, nullptr);
  finalize_k<<<dim3(6), 256, 0, stream>>>(rowsumR, amax, diagv, out);
}